// Round 16
// baseline (154.603 us; speedup 1.0000x reference)
//
#include <hip/hip_runtime.h>
#include <hip/hip_bf16.h>
#include <math.h>

// Mamba block forward. All matmuls bf16 MFMA; bf16 activations end-to-end.
// GEMM1: 128² tiles, split-K=2 (1024 blocks = 4/CU concurrency), XCD swizzle,
// bf16 partials summed IN CONSUMERS (conv, scan_pass3) — no reduce pass.
// GEMM7: 128² split-K=4 XCD-swizzled, bf16 partials + reduce4. Skinny K=128
// GEMMs: 64² tiles. Segmented scan (8 seg) with inline h0 compose.
// Shapes: B=2, L=1024, DIM=1024, DIM_INNER=2048, D_STATE=16, D_CONV=4, DT_RANK=64

__device__ __forceinline__ float silu_f(float x) {
    return x / (1.f + __expf(-x));
}
__device__ __forceinline__ unsigned short f2bf(float f) {
    __hip_bfloat16 h = __float2bfloat16(f);
    return *(unsigned short*)&h;
}
__device__ __forceinline__ float bf2f(unsigned short u) {
    return __uint_as_float((unsigned)u << 16);
}

typedef __attribute__((ext_vector_type(8))) short short8v;
typedef __attribute__((ext_vector_type(4))) float f32x4;

__device__ __forceinline__ void gload16(const void* g, void* lds) {
    __builtin_amdgcn_global_load_lds(
        (const __attribute__((address_space(1))) unsigned int*)g,
        (__attribute__((address_space(3))) unsigned int*)lds, 16, 0, 0);
}

// ---------------- 128x128 bf16 MFMA GEMM core ------------------------------
// MODE 0: fp32 C.  MODE 4: bf16 Cb = v, paired stores.
template<int MODE>
__device__ __forceinline__ void gemm_core(
    const unsigned short* __restrict__ A,
    const unsigned short* __restrict__ BT,
    float* __restrict__ C, unsigned short* __restrict__ Cb,
    int M, int N, int K, int kbeg, int klen,
    int bx, int by, unsigned short* As, unsigned short* Bs)
{
    const int tid  = threadIdx.x;
    const int wid  = tid >> 6;
    const int lane = tid & 63;
    const int wr = wid >> 1, wc = wid & 1;
    const int row0 = by * 128, col0 = bx * 128;

    f32x4 acc[4][4] = {};

    const int srow = lane >> 2;
    const int scol = (lane & 3) * 8;

    for (int k0 = kbeg; k0 < kbeg + klen; k0 += 32) {
        #pragma unroll
        for (int c = 0; c < 2; ++c) {
            int chunk = wid * 2 + c;
            gload16(A  + (size_t)(row0 + chunk * 16 + srow) * K + k0 + scol,
                    (void*)(As + chunk * 512));
            gload16(BT + (size_t)(col0 + chunk * 16 + srow) * K + k0 + scol,
                    (void*)(Bs + chunk * 512));
        }
        __syncthreads();
        short8v a[4], b[4];
        #pragma unroll
        for (int i = 0; i < 4; ++i)
            a[i] = *(const short8v*)&As[(wr * 64 + i * 16 + (lane & 15)) * 32 + (lane >> 4) * 8];
        #pragma unroll
        for (int j = 0; j < 4; ++j)
            b[j] = *(const short8v*)&Bs[(wc * 64 + j * 16 + (lane & 15)) * 32 + (lane >> 4) * 8];
        #pragma unroll
        for (int i = 0; i < 4; ++i)
            #pragma unroll
            for (int j = 0; j < 4; ++j)
                acc[i][j] = __builtin_amdgcn_mfma_f32_16x16x32_bf16(a[i], b[j], acc[i][j], 0, 0, 0);
        __syncthreads();
    }

    #pragma unroll
    for (int i = 0; i < 4; ++i) {
        int rbase = row0 + wr * 64 + i * 16 + (lane >> 4) * 4;
        #pragma unroll
        for (int j = 0; j < 4; ++j) {
            int cc = col0 + wc * 64 + j * 16 + (lane & 15);
            #pragma unroll
            for (int r = 0; r < 4; ++r) {
                float v = acc[i][j][r];
                if (MODE == 0) {
                    C[(size_t)(rbase + r) * N + cc] = v;
                } else {
                    unsigned short m = f2bf(v);
                    unsigned other = (unsigned)__shfl_xor((int)m, 1, 64) & 0xffffu;
                    if (!(lane & 1))
                        *(unsigned*)(Cb + (size_t)(rbase + r) * N + cc) =
                            (unsigned)m | (other << 16);
                }
            }
        }
    }
}

// ---------------- GEMM7: ys @ W_out, 128², split-K=4, XCD-swizzled, bf16 partials
__global__ __launch_bounds__(256) void gemm7_swz(
    const unsigned short* __restrict__ A,    // ysb [2048][2048]
    const unsigned short* __restrict__ BT,   // W_outT [1024][2048]
    unsigned short* __restrict__ Pb)         // 4 bf16 partials [2048][1024]
{
    __shared__ unsigned short As[128 * 32];
    __shared__ unsigned short Bs[128 * 32];
    const int bid = blockIdx.x;
    const int xcd = bid & 7, idx = bid >> 3;
    const int kz = xcd >> 1;
    const int by = (xcd & 1) * 8 + (idx >> 3);
    const int bx = idx & 7;
    gemm_core<4>(A, BT, nullptr, Pb + (size_t)kz * 2048 * 1024,
                 2048, 1024, 2048, kz * 512, 512, bx, by, As, Bs);
}

// ---------------- 64x64-tile bf16 MFMA GEMM (skinny K=128 GEMMs) -----------
// MODE 3: bf16 Cb = softplus(v + bias). MODE 5: bf16 partial (Cb + z*M*N).
template<int MODE>
__global__ __launch_bounds__(256) void gemm64_bf16(
    const unsigned short* __restrict__ A,
    const unsigned short* __restrict__ BT,
    unsigned short* __restrict__ Cb,
    const float* __restrict__ bias,
    int M, int N, int K, int klen)
{
    __shared__ unsigned short As[64 * 32];
    __shared__ unsigned short Bs[64 * 32];
    const int tid  = threadIdx.x;
    const int wid  = tid >> 6;
    const int lane = tid & 63;
    const int wr = wid >> 1, wc = wid & 1;
    const int row0 = blockIdx.y * 64, col0 = blockIdx.x * 64;
    const int kbeg = blockIdx.z * klen;
    if (MODE == 5) Cb += (size_t)blockIdx.z * M * N;

    f32x4 acc[2][2] = {};
    const int srow = lane >> 2;
    const int scol = (lane & 3) * 8;

    for (int k0 = kbeg; k0 < kbeg + klen; k0 += 32) {
        gload16(A  + (size_t)(row0 + wid * 16 + srow) * K + k0 + scol,
                (void*)(As + wid * 512));
        gload16(BT + (size_t)(col0 + wid * 16 + srow) * K + k0 + scol,
                (void*)(Bs + wid * 512));
        __syncthreads();
        short8v a[2], b[2];
        #pragma unroll
        for (int i = 0; i < 2; ++i)
            a[i] = *(const short8v*)&As[(wr * 32 + i * 16 + (lane & 15)) * 32 + (lane >> 4) * 8];
        #pragma unroll
        for (int j = 0; j < 2; ++j)
            b[j] = *(const short8v*)&Bs[(wc * 32 + j * 16 + (lane & 15)) * 32 + (lane >> 4) * 8];
        #pragma unroll
        for (int i = 0; i < 2; ++i)
            #pragma unroll
            for (int j = 0; j < 2; ++j)
                acc[i][j] = __builtin_amdgcn_mfma_f32_16x16x32_bf16(a[i], b[j], acc[i][j], 0, 0, 0);
        __syncthreads();
    }

    #pragma unroll
    for (int i = 0; i < 2; ++i) {
        int rbase = row0 + wr * 32 + i * 16 + (lane >> 4) * 4;
        #pragma unroll
        for (int j = 0; j < 2; ++j) {
            int cc = col0 + wc * 32 + j * 16 + (lane & 15);
            float bi = (MODE == 3) ? bias[cc] : 0.f;
            #pragma unroll
            for (int r = 0; r < 4; ++r) {
                float v = acc[i][j][r];
                if (MODE == 3) {
                    v += bi;
                    v = (v > 20.f) ? v : __logf(1.f + __expf(v));
                }
                unsigned short m = f2bf(v);
                unsigned other = (unsigned)__shfl_xor((int)m, 1, 64) & 0xffffu;
                if (!(lane & 1))
                    *(unsigned*)(Cb + (size_t)(rbase + r) * N + cc) =
                        (unsigned)m | (other << 16);
            }
        }
    }
}

// 64x64 fp32->bf16 transpose tile; paired short2 stores.
__device__ __forceinline__ void trans64(
    const float* __restrict__ W, unsigned short* __restrict__ WT,
    int K, int N, int bk, int bn, int tid, float (*t)[65])
{
    const int tx = tid & 63, ty = tid >> 6;
    #pragma unroll
    for (int s = 0; s < 16; ++s)
        t[ty + 4 * s][tx] = W[(size_t)(bk + ty + 4 * s) * N + bn + tx];
    __syncthreads();
    const int c = tid & 31, rg = tid >> 5;
    #pragma unroll
    for (int s = 0; s < 8; ++s) {
        int r = rg + 8 * s;
        unsigned lo = f2bf(t[2 * c][r]);
        unsigned hi = f2bf(t[2 * c + 1][r]);
        *(unsigned*)(WT + (size_t)(bn + r) * K + bk + 2 * c) = lo | (hi << 16);
    }
}

// ---------------- GEMM1 (split-K=2, XCD-swizzled) + weight transposes -------
// blocks [0,1024)     : xr partials = x @ W_in (kz = idx>>6); bf16 out
// blocks [1024,1536)  : W_out -> W_outT
// blocks [1536,1792)  : W_x -> W_xTp
// blocks [1792,2048)  : W_dt -> W_dtTp
__global__ __launch_bounds__(256) void gemm1_fused(
    const unsigned short* __restrict__ xb,
    const unsigned short* __restrict__ W_inT,
    unsigned short* __restrict__ xr_p,       // [2][2048][4096] bf16 partials
    const float* __restrict__ W_out,
    const float* __restrict__ Wx,
    const float* __restrict__ Wdt,
    unsigned short* __restrict__ W_outT,
    unsigned short* __restrict__ W_xTp,
    unsigned short* __restrict__ W_dtTp)
{
    __shared__ char smem[64 * 65 * 4];
    const int bid = blockIdx.x;
    const int tid = threadIdx.x;
    if (bid < 1024) {
        unsigned short* As = (unsigned short*)smem;
        unsigned short* Bs = As + 128 * 32;
        const int xcd = bid & 7, idx = bid >> 3;      // idx 0..127
        const int kz = idx >> 6;                      // 0/1
        const int i  = idx & 63;
        const int bx = (xcd & 3) * 8 + (i & 7);       // 0..31
        const int by = (xcd >> 2) * 8 + (i >> 3);     // 0..15
        gemm_core<4>(xb, W_inT, nullptr, xr_p + (size_t)kz * 2048 * 4096,
                     2048, 4096, 1024, kz * 512, 512, bx, by, As, Bs);
    } else if (bid < 1536) {
        int tt = bid - 1024;
        trans64(W_out, W_outT, 2048, 1024, (tt >> 4) * 64, (tt & 15) * 64,
                tid, (float(*)[65])smem);
    } else if (bid < 1792) {
        int idx4 = (bid - 1536) * 256 + tid;
        int n = idx4 >> 9, k0 = (idx4 & 511) << 2;
        ushort4 o;
        o.x = f2bf((n < 96) ? Wx[(size_t)(k0 + 0) * 96 + n] : 0.f);
        o.y = f2bf((n < 96) ? Wx[(size_t)(k0 + 1) * 96 + n] : 0.f);
        o.z = f2bf((n < 96) ? Wx[(size_t)(k0 + 2) * 96 + n] : 0.f);
        o.w = f2bf((n < 96) ? Wx[(size_t)(k0 + 3) * 96 + n] : 0.f);
        *(ushort4*)(W_xTp + (size_t)idx4 * 4) = o;
    } else {
        int idx4 = (bid - 1792) * 256 + tid;
        int n = idx4 >> 5, k0 = (idx4 & 31) << 2;
        ushort4 o;
        o.x = f2bf((k0 + 0 < 64) ? Wdt[(size_t)(k0 + 0) * 2048 + n] : 0.f);
        o.y = f2bf((k0 + 1 < 64) ? Wdt[(size_t)(k0 + 1) * 2048 + n] : 0.f);
        o.z = f2bf((k0 + 2 < 64) ? Wdt[(size_t)(k0 + 2) * 2048 + n] : 0.f);
        o.w = f2bf((k0 + 3 < 64) ? Wdt[(size_t)(k0 + 3) * 2048 + n] : 0.f);
        *(ushort4*)(W_dtTp + (size_t)idx4 * 4) = o;
    }
}

// ---------------- prep: x -> bf16, W_in -> W_inT ----------------------------
__global__ __launch_bounds__(256) void prep(
    const float* __restrict__ x,
    const float* __restrict__ W_in,
    unsigned short* __restrict__ xb,
    unsigned short* __restrict__ W_inT)
{
    __shared__ float t[64][65];
    const int bid = blockIdx.x;
    const int tid = threadIdx.x;
    if (bid < 1024) {
        int i = bid * 256 + tid;
        float4 v0 = *(const float4*)(x + (size_t)i * 8);
        float4 v1 = *(const float4*)(x + (size_t)i * 8 + 4);
        ushort4 o0, o1;
        o0.x = f2bf(v0.x); o0.y = f2bf(v0.y); o0.z = f2bf(v0.z); o0.w = f2bf(v0.w);
        o1.x = f2bf(v1.x); o1.y = f2bf(v1.y); o1.z = f2bf(v1.z); o1.w = f2bf(v1.w);
        *(ushort4*)(xb + (size_t)i * 8) = o0;
        *(ushort4*)(xb + (size_t)i * 8 + 4) = o1;
    } else {
        int tt = bid - 1024;
        trans64(W_in, W_inT, 1024, 4096, (tt >> 6) * 64, (tt & 63) * 64, tid, t);
    }
}

// xdbl_b[2048][128] = bf16 sum of 16 bf16 split-K partials (fp32 accumulate).
__global__ __launch_bounds__(256) void reduce16(
    const unsigned short* __restrict__ P, unsigned short* __restrict__ dstb)
{
    int i = blockIdx.x * 256 + threadIdx.x;   // uint4 index, 32768 total
    float s[8] = {};
    #pragma unroll
    for (int k = 0; k < 16; ++k) {
        uint4 v = ((const uint4*)P)[i + (size_t)k * 32768];
        const unsigned short* pv = (const unsigned short*)&v;
        #pragma unroll
        for (int e = 0; e < 8; ++e) s[e] += bf2f(pv[e]);
    }
    unsigned short ob[8];
    #pragma unroll
    for (int e = 0; e < 8; ++e) ob[e] = f2bf(s[e]);
    ((uint4*)dstb)[i] = *(const uint4*)ob;
}

// out[2048][1024] = sum of 4 bf16 split-K partials (fp32 accumulate)
__global__ __launch_bounds__(256) void reduce4(
    const unsigned short* __restrict__ P, float* __restrict__ dst)
{
    int i = blockIdx.x * 256 + threadIdx.x;   // uint4 index, 262144 total
    float s[8] = {};
    #pragma unroll
    for (int k = 0; k < 4; ++k) {
        uint4 v = ((const uint4*)P)[i + (size_t)k * 262144];
        const unsigned short* pv = (const unsigned short*)&v;
        #pragma unroll
        for (int e = 0; e < 8; ++e) s[e] += bf2f(pv[e]);
    }
    ((float4*)dst)[i * 2]     = make_float4(s[0], s[1], s[2], s[3]);
    ((float4*)dst)[i * 2 + 1] = make_float4(s[4], s[5], s[6], s[7]);
}

// u(bf16) = silu(causal dwconv((xr_p0 + xr_p1)[:, :2048]) + conv_b), 4 ch/thr
__global__ __launch_bounds__(256) void conv_silu(
    const unsigned short* __restrict__ xp0,   // [2048][4096] bf16 partial 0
    const unsigned short* __restrict__ xp1,   // partial 1
    const float* __restrict__ conv_w,
    const float* __restrict__ conv_b,
    unsigned short* __restrict__ ub)
{
    int t = blockIdx.x * 256 + threadIdx.x;
    int d4 = (t & 511) << 2;
    int r = t >> 9;
    int l = r & 1023, b = r >> 10;
    float4 cb4 = *(const float4*)(conv_b + d4);
    float acc[4] = {cb4.x, cb4.y, cb4.z, cb4.w};
    float4 cw0 = *(const float4*)(conv_w + (size_t)(d4 + 0) * 4);
    float4 cw1 = *(const float4*)(conv_w + (size_t)(d4 + 1) * 4);
    float4 cw2 = *(const float4*)(conv_w + (size_t)(d4 + 2) * 4);
    float4 cw3 = *(const float4*)(conv_w + (size_t)(d4 + 3) * 4);
    float w0a[4] = {cw0.x, cw0.y, cw0.z, cw0.w};
    float w1a[4] = {cw1.x, cw1.y, cw1.z, cw1.w};
    float w2a[4] = {cw2.x, cw2.y, cw2.z, cw2.w};
    float w3a[4] = {cw3.x, cw3.y, cw3.z, cw3.w};
    #pragma unroll
    for (int w = 0; w < 4; ++w) {
        int ls = l + w - 3;
        if (ls >= 0) {
            size_t off = (((size_t)((b << 10) + ls)) << 12) + d4;
            ushort4 x0 = *(const ushort4*)(xp0 + off);
            ushort4 x1 = *(const ushort4*)(xp1 + off);
            acc[0] = fmaf(bf2f(x0.x) + bf2f(x1.x), w0a[w], acc[0]);
            acc[1] = fmaf(bf2f(x0.y) + bf2f(x1.y), w1a[w], acc[1]);
            acc[2] = fmaf(bf2f(x0.z) + bf2f(x1.z), w2a[w], acc[2]);
            acc[3] = fmaf(bf2f(x0.w) + bf2f(x1.w), w3a[w], acc[3]);
        }
    }
    ushort4 o;
    o.x = f2bf(silu_f(acc[0]));
    o.y = f2bf(silu_f(acc[1]));
    o.z = f2bf(silu_f(acc[2]));
    o.w = f2bf(silu_f(acc[3]));
    *(ushort4*)(ub + (size_t)t * 4) = o;
}

// ---------------- segmented selective scan (bf16 inputs) -------------------
#define SCAN_T 16
#define NSEG 8
#define SEGLEN 128

#define DPP_ADD(v, ctrl) ((v) + __int_as_float(__builtin_amdgcn_update_dpp( \
        0, __float_as_int(v), (ctrl), 0xF, 0xF, true)))

__global__ __launch_bounds__(256) void scan_pass1(
    const unsigned short* __restrict__ delta_b,
    const unsigned short* __restrict__ ub,
    const unsigned short* __restrict__ xdbl_b,  // [2048][128] bf16
    const float* __restrict__ A_log,
    float* __restrict__ stash)
{
    __shared__ float2 du[2][SCAN_T][17];
    __shared__ float  bs[2][SCAN_T][17];

    const int tid = threadIdx.x;
    const int dg = blockIdx.x, b = blockIdx.y, s = blockIdx.z;
    const int d0 = dg * 16;
    const int ch = tid >> 4, n = tid & 15;
    const float Aval = -__expf(A_log[(d0 + ch) * 16 + n]);
    const int sli = tid >> 4, sc = tid & 15;
    const int lbase = s * SEGLEN;

    float g_d, g_u, g_b;
    {
        size_t row = (size_t)(b << 10) + lbase + sli;
        g_d = bf2f(delta_b[(row << 11) + d0 + sc]);
        g_u = bf2f(ub[(row << 11) + d0 + sc]);
        g_b = bf2f(xdbl_b[(row << 7) + 64 + sc]);
    }
    du[0][sli][sc] = make_float2(g_d, g_u);
    bs[0][sli][sc] = g_b;
    __syncthreads();

    float h = 0.f, sd = 0.f;
    int cb = 0;
    for (int c = 0; c < SEGLEN / SCAN_T; ++c) {
        const bool more = (c + 1) < SEGLEN / SCAN_T;
        if (more) {
            size_t row = (size_t)(b << 10) + lbase + (c + 1) * SCAN_T + sli;
            g_d = bf2f(delta_b[(row << 11) + d0 + sc]);
            g_u = bf2f(ub[(row << 11) + d0 + sc]);
            g_b = bf2f(xdbl_b[(row << 7) + 64 + sc]);
        }
        float e_[SCAN_T], f_[SCAN_T];
        #pragma unroll
        for (int li = 0; li < SCAN_T; ++li) {
            float2 duv = du[cb][li][ch];
            float bv = bs[cb][li][n];
            e_[li] = __expf(duv.x * Aval);
            f_[li] = duv.x * bv * duv.y;
            sd += duv.x;
        }
        #pragma unroll
        for (int li = 0; li < SCAN_T; ++li)
            h = fmaf(e_[li], h, f_[li]);
        if (more) {
            du[cb ^ 1][sli][sc] = make_float2(g_d, g_u);
            bs[cb ^ 1][sli][sc] = g_b;
        }
        __syncthreads();
        cb ^= 1;
    }
    int j = (((b << 3) + s) * 128 + dg) * 256 + tid;
    stash[j] = __expf(Aval * sd);
    stash[j + 524288] = h;
}

__global__ __launch_bounds__(256) void scan_pass3(
    const unsigned short* __restrict__ delta_b,
    const unsigned short* __restrict__ ub,
    const unsigned short* __restrict__ xdbl_b,
    const float* __restrict__ A_log,
    const unsigned short* __restrict__ xp0,   // res partial 0 (cols 2048+)
    const unsigned short* __restrict__ xp1,   // res partial 1
    const float* __restrict__ stash,
    const float* __restrict__ Dv,
    unsigned short* __restrict__ ysb)
{
    __shared__ float2 du[2][SCAN_T][17];
    __shared__ float2 bc[2][SCAN_T][17];
    __shared__ float  rs[2][SCAN_T][17];

    const int tid = threadIdx.x;
    const int dg = blockIdx.x, b = blockIdx.y, s = blockIdx.z;
    const int d0 = dg * 16;
    const int ch = tid >> 4, n = tid & 15;
    const float Aval = -__expf(A_log[(d0 + ch) * 16 + n]);
    const float Dval = Dv[d0 + ch];
    const int sli = tid >> 4, sc = tid & 15;
    const int lbase = s * SEGLEN;

    float h = 0.f;
    for (int sp = 0; sp < s; ++sp) {
        int j = (((b << 3) + sp) * 128 + dg) * 256 + tid;
        h = fmaf(stash[j], h, stash[j + 524288]);
    }

    float g_d, g_u, g_b, g_c, g_r;
    {
        size_t row = (size_t)(b << 10) + lbase + sli;
        g_d = bf2f(delta_b[(row << 11) + d0 + sc]);
        g_u = bf2f(ub[(row << 11) + d0 + sc]);
        g_b = bf2f(xdbl_b[(row << 7) + 64 + sc]);
        g_c = bf2f(xdbl_b[(row << 7) + 80 + sc]);
        size_t roff = (row << 12) + 2048 + d0 + sc;
        g_r = bf2f(xp0[roff]) + bf2f(xp1[roff]);
    }
    du[0][sli][sc] = make_float2(g_d, g_u);
    bc[0][sli][sc] = make_float2(g_b, g_c);
    rs[0][sli][sc] = g_r;
    __syncthreads();

    int cb = 0;
    for (int c = 0; c < SEGLEN / SCAN_T; ++c) {
        const int l0 = lbase + c * SCAN_T;
        const bool more = (c + 1) < SEGLEN / SCAN_T;
        if (more) {
            size_t row = (size_t)(b << 10) + l0 + SCAN_T + sli;
            g_d = bf2f(delta_b[(row << 11) + d0 + sc]);
            g_u = bf2f(ub[(row << 11) + d0 + sc]);
            g_b = bf2f(xdbl_b[(row << 7) + 64 + sc]);
            g_c = bf2f(xdbl_b[(row << 7) + 80 + sc]);
            size_t roff = (row << 12) + 2048 + d0 + sc;
            g_r = bf2f(xp0[roff]) + bf2f(xp1[roff]);
        }
        float e_[SCAN_T], f_[SCAN_T], c_[SCAN_T];
        #pragma unroll
        for (int li = 0; li < SCAN_T; ++li) {
            float2 duv = du[cb][li][ch];
            float2 bcv = bc[cb][li][n];
            e_[li] = __expf(duv.x * Aval);
            f_[li] = duv.x * bcv.x * duv.y;
            c_[li] = bcv.y;
        }
        float mysum = 0.f;
        #pragma unroll
        for (int li = 0; li < SCAN_T; ++li) {
            h = fmaf(e_[li], h, f_[li]);
            float pv = h * c_[li];
            pv = DPP_ADD(pv, 0xB1);
            pv = DPP_ADD(pv, 0x4E);
            pv = DPP_ADD(pv, 0x141);
            pv = DPP_ADD(pv, 0x140);
            mysum = (n == li) ? pv : mysum;
        }
        {
            float2 duv = du[cb][n][ch];
            float resv = rs[cb][n][ch];
            float outv = (mysum + duv.y * Dval) * silu_f(resv);
            ysb[((size_t)((b << 10) + l0 + n) << 11) + d0 + ch] = f2bf(outv);
        }
        if (more) {
            du[cb ^ 1][sli][sc] = make_float2(g_d, g_u);
            bc[cb ^ 1][sli][sc] = make_float2(g_b, g_c);
            rs[cb ^ 1][sli][sc] = g_r;
        }
        __syncthreads();
        cb ^= 1;
    }
}

extern "C" void kernel_launch(void* const* d_in, const int* in_sizes, int n_in,
                              void* d_out, int out_size, void* d_ws, size_t ws_size,
                              hipStream_t stream)
{
    const float* x      = (const float*)d_in[0];
    const float* W_in   = (const float*)d_in[1];
    const float* conv_w = (const float*)d_in[2];
    const float* conv_b = (const float*)d_in[3];
    const float* W_x    = (const float*)d_in[4];
    const float* W_dt   = (const float*)d_in[5];
    const float* b_dt   = (const float*)d_in[6];
    const float* A_log  = (const float*)d_in[7];
    const float* Dv     = (const float*)d_in[8];
    const float* W_out  = (const float*)d_in[9];
    float* out = (float*)d_out;

    float* ws    = (float*)d_ws;
    unsigned short* P16b = (unsigned short*)(ws + (size_t)262144);   // 16 bf16 partials [2048][128]
    unsigned short* P4b  = (unsigned short*)(ws + (size_t)4456448);  // 4 bf16 partials [2048][1024]
    float* stash = ws + (size_t)12845056;            // 1,048,576 f (A_seg,B_seg)
    unsigned short* bfr = (unsigned short*)(ws + (size_t)13893632);
    unsigned short* xb      = bfr;                       // [2048][1024]
    unsigned short* W_inT   = bfr + (size_t)2097152;     // [4096][1024]
    unsigned short* W_xTp   = bfr + (size_t)6291456;     // [128][2048]
    unsigned short* W_dtTp  = bfr + (size_t)6553600;     // [2048][128]
    unsigned short* W_outT  = bfr + (size_t)6815744;     // [1024][2048]
    unsigned short* xr_p    = bfr + (size_t)8912896;     // 2 x [2048][4096] partials
    unsigned short* xp0     = xr_p;
    unsigned short* xp1     = xr_p + (size_t)8388608;
    unsigned short* ub      = bfr + (size_t)25690112;    // [2048][2048]
    unsigned short* delta_b = bfr + (size_t)29884416;    // [2048][2048]
    unsigned short* ysb     = bfr + (size_t)34078720;    // [2048][2048]
    unsigned short* xdbl_b  = bfr + (size_t)38273024;    // [2048][128]

    // 1. x -> bf16, W_in -> W_inT
    prep<<<2048, 256, 0, stream>>>(x, W_in, xb, W_inT);
    // 2. GEMM1 128² tiles, split-K=2 (1024 blocks, 4/CU), XCD swizzle + transposes
    gemm1_fused<<<2048, 256, 0, stream>>>(xb, W_inT, xr_p, W_out, W_x, W_dt,
                                          W_outT, W_xTp, W_dtTp);
    // 3. u(bf16) = silu(causal dwconv(xp0+xp1)); partials summed here
    conv_silu<<<4096, 256, 0, stream>>>(xp0, xp1, conv_w, conv_b, ub);
    // 4. xdbl_b = u @ W_x  64²-tile split-K=16 (1024 blocks), bf16 partials
    gemm64_bf16<5><<<dim3(2, 32, 16), 256, 0, stream>>>(ub, W_xTp, P16b, nullptr, 2048, 128, 2048, 128);
    reduce16<<<128, 256, 0, stream>>>(P16b, xdbl_b);
    // 5. delta(bf16) = softplus(xdbl @ W_dt + b_dt)  64²-tile (1024 blocks)
    gemm64_bf16<3><<<dim3(32, 32, 1), 256, 0, stream>>>(xdbl_b, W_dtTp, delta_b, b_dt, 2048, 2048, 128, 128);
    // 6. segmented scan: per-segment maps -> replay (h0 composed inline)
    scan_pass1<<<dim3(128, 2, 8), 256, 0, stream>>>(delta_b, ub, xdbl_b, A_log, stash);
    scan_pass3<<<dim3(128, 2, 8), 256, 0, stream>>>(delta_b, ub, xdbl_b, A_log, xp0, xp1, stash, Dv, ysb);
    // 7. out = ys @ W_out  128² tiles, split-K=4, XCD-swizzled, bf16 partials
    gemm7_swz<<<512, 256, 0, stream>>>(ysb, W_outT, P4b);
    reduce4<<<1024, 256, 0, stream>>>(P4b, out);
}

// Round 17
// 142.429 us; speedup vs baseline: 1.0855x; 1.0855x over previous
//
#include <hip/hip_runtime.h>
#include <hip/hip_bf16.h>
#include <math.h>

// Mamba block forward. All matmuls bf16 MFMA; bf16 activations end-to-end;
// 128x128 tiles + XCD swizzle on big GEMMs, DOUBLE-BUFFERED K-loop (stage
// next tile before compute, single barrier/K-step); bf16 split-K partials;
// 64x64 tiles for skinny K=128 GEMMs; segmented scan (8 seg).
// Shapes: B=2, L=1024, DIM=1024, DIM_INNER=2048, D_STATE=16, D_CONV=4, DT_RANK=64

__device__ __forceinline__ float silu_f(float x) {
    return x / (1.f + __expf(-x));
}
__device__ __forceinline__ unsigned short f2bf(float f) {
    __hip_bfloat16 h = __float2bfloat16(f);
    return *(unsigned short*)&h;
}
__device__ __forceinline__ float bf2f(unsigned short u) {
    return __uint_as_float((unsigned)u << 16);
}

typedef __attribute__((ext_vector_type(8))) short short8v;
typedef __attribute__((ext_vector_type(4))) float f32x4;

__device__ __forceinline__ void gload16(const void* g, void* lds) {
    __builtin_amdgcn_global_load_lds(
        (const __attribute__((address_space(1))) unsigned int*)g,
        (__attribute__((address_space(3))) unsigned int*)lds, 16, 0, 0);
}

// ---------------- 128x128 bf16 MFMA GEMM core, double-buffered -------------
// As/Bs each 2*128*32 ushorts. Stage tile t+1 BEFORE computing tile t; one
// vmcnt(0)+barrier per K-step (compiler emits it inside __syncthreads) so
// global-load latency hides under ds_read+MFMA.
// MODE 0: fp32 C.  MODE 4: bf16 Cb = v, paired stores.
template<int MODE>
__device__ __forceinline__ void gemm_core(
    const unsigned short* __restrict__ A,
    const unsigned short* __restrict__ BT,
    float* __restrict__ C, unsigned short* __restrict__ Cb,
    int M, int N, int K, int kbeg, int klen,
    int bx, int by, unsigned short* As, unsigned short* Bs)
{
    const int tid  = threadIdx.x;
    const int wid  = tid >> 6;
    const int lane = tid & 63;
    const int wr = wid >> 1, wc = wid & 1;
    const int row0 = by * 128, col0 = bx * 128;

    f32x4 acc[4][4] = {};

    const int srow = lane >> 2;
    const int scol = (lane & 3) * 8;

    // prologue: stage tile 0 into buffer 0
    #pragma unroll
    for (int c = 0; c < 2; ++c) {
        int chunk = wid * 2 + c;
        gload16(A  + (size_t)(row0 + chunk * 16 + srow) * K + kbeg + scol,
                (void*)(As + chunk * 512));
        gload16(BT + (size_t)(col0 + chunk * 16 + srow) * K + kbeg + scol,
                (void*)(Bs + chunk * 512));
    }
    __syncthreads();

    int cur = 0;
    for (int k0 = kbeg; k0 < kbeg + klen; k0 += 32) {
        const int nxt = cur ^ 1;
        if (k0 + 32 < kbeg + klen) {
            #pragma unroll
            for (int c = 0; c < 2; ++c) {
                int chunk = wid * 2 + c;
                gload16(A  + (size_t)(row0 + chunk * 16 + srow) * K + (k0 + 32) + scol,
                        (void*)(As + nxt * 4096 + chunk * 512));
                gload16(BT + (size_t)(col0 + chunk * 16 + srow) * K + (k0 + 32) + scol,
                        (void*)(Bs + nxt * 4096 + chunk * 512));
            }
        }
        short8v a[4], b[4];
        #pragma unroll
        for (int i = 0; i < 4; ++i)
            a[i] = *(const short8v*)&As[cur * 4096 + (wr * 64 + i * 16 + (lane & 15)) * 32 + (lane >> 4) * 8];
        #pragma unroll
        for (int j = 0; j < 4; ++j)
            b[j] = *(const short8v*)&Bs[cur * 4096 + (wc * 64 + j * 16 + (lane & 15)) * 32 + (lane >> 4) * 8];
        #pragma unroll
        for (int i = 0; i < 4; ++i)
            #pragma unroll
            for (int j = 0; j < 4; ++j)
                acc[i][j] = __builtin_amdgcn_mfma_f32_16x16x32_bf16(a[i], b[j], acc[i][j], 0, 0, 0);
        __syncthreads();   // drains vmcnt (next tile) + lgkm; releases buffers
        cur = nxt;
    }

    #pragma unroll
    for (int i = 0; i < 4; ++i) {
        int rbase = row0 + wr * 64 + i * 16 + (lane >> 4) * 4;
        #pragma unroll
        for (int j = 0; j < 4; ++j) {
            int cc = col0 + wc * 64 + j * 16 + (lane & 15);
            #pragma unroll
            for (int r = 0; r < 4; ++r) {
                float v = acc[i][j][r];
                if (MODE == 0) {
                    C[(size_t)(rbase + r) * N + cc] = v;
                } else {
                    unsigned short m = f2bf(v);
                    unsigned other = (unsigned)__shfl_xor((int)m, 1, 64) & 0xffffu;
                    if (!(lane & 1))
                        *(unsigned*)(Cb + (size_t)(rbase + r) * N + cc) =
                            (unsigned)m | (other << 16);
                }
            }
        }
    }
}

// ---------------- GEMM7: ys @ W_out, 128², split-K=4, XCD-swizzled, bf16 partials
__global__ __launch_bounds__(256) void gemm7_swz(
    const unsigned short* __restrict__ A,    // ysb [2048][2048]
    const unsigned short* __restrict__ BT,   // W_outT [1024][2048]
    unsigned short* __restrict__ Pb)         // 4 bf16 partials [2048][1024]
{
    __shared__ unsigned short As[2 * 128 * 32];
    __shared__ unsigned short Bs[2 * 128 * 32];
    const int bid = blockIdx.x;
    const int xcd = bid & 7, idx = bid >> 3;
    const int kz = xcd >> 1;
    const int by = (xcd & 1) * 8 + (idx >> 3);
    const int bx = idx & 7;
    gemm_core<4>(A, BT, nullptr, Pb + (size_t)kz * 2048 * 1024,
                 2048, 1024, 2048, kz * 512, 512, bx, by, As, Bs);
}

// ---------------- 64x64-tile bf16 MFMA GEMM (skinny K=128 GEMMs) -----------
// MODE 3: bf16 Cb = softplus(v + bias). MODE 5: bf16 partial (Cb + z*M*N).
template<int MODE>
__global__ __launch_bounds__(256) void gemm64_bf16(
    const unsigned short* __restrict__ A,
    const unsigned short* __restrict__ BT,
    unsigned short* __restrict__ Cb,
    const float* __restrict__ bias,
    int M, int N, int K, int klen)
{
    __shared__ unsigned short As[64 * 32];
    __shared__ unsigned short Bs[64 * 32];
    const int tid  = threadIdx.x;
    const int wid  = tid >> 6;
    const int lane = tid & 63;
    const int wr = wid >> 1, wc = wid & 1;
    const int row0 = blockIdx.y * 64, col0 = blockIdx.x * 64;
    const int kbeg = blockIdx.z * klen;
    if (MODE == 5) Cb += (size_t)blockIdx.z * M * N;

    f32x4 acc[2][2] = {};
    const int srow = lane >> 2;
    const int scol = (lane & 3) * 8;

    for (int k0 = kbeg; k0 < kbeg + klen; k0 += 32) {
        gload16(A  + (size_t)(row0 + wid * 16 + srow) * K + k0 + scol,
                (void*)(As + wid * 512));
        gload16(BT + (size_t)(col0 + wid * 16 + srow) * K + k0 + scol,
                (void*)(Bs + wid * 512));
        __syncthreads();
        short8v a[2], b[2];
        #pragma unroll
        for (int i = 0; i < 2; ++i)
            a[i] = *(const short8v*)&As[(wr * 32 + i * 16 + (lane & 15)) * 32 + (lane >> 4) * 8];
        #pragma unroll
        for (int j = 0; j < 2; ++j)
            b[j] = *(const short8v*)&Bs[(wc * 32 + j * 16 + (lane & 15)) * 32 + (lane >> 4) * 8];
        #pragma unroll
        for (int i = 0; i < 2; ++i)
            #pragma unroll
            for (int j = 0; j < 2; ++j)
                acc[i][j] = __builtin_amdgcn_mfma_f32_16x16x32_bf16(a[i], b[j], acc[i][j], 0, 0, 0);
        __syncthreads();
    }

    #pragma unroll
    for (int i = 0; i < 2; ++i) {
        int rbase = row0 + wr * 32 + i * 16 + (lane >> 4) * 4;
        #pragma unroll
        for (int j = 0; j < 2; ++j) {
            int cc = col0 + wc * 32 + j * 16 + (lane & 15);
            float bi = (MODE == 3) ? bias[cc] : 0.f;
            #pragma unroll
            for (int r = 0; r < 4; ++r) {
                float v = acc[i][j][r];
                if (MODE == 3) {
                    v += bi;
                    v = (v > 20.f) ? v : __logf(1.f + __expf(v));
                }
                unsigned short m = f2bf(v);
                unsigned other = (unsigned)__shfl_xor((int)m, 1, 64) & 0xffffu;
                if (!(lane & 1))
                    *(unsigned*)(Cb + (size_t)(rbase + r) * N + cc) =
                        (unsigned)m | (other << 16);
            }
        }
    }
}

// 64x64 fp32->bf16 transpose tile; paired short2 stores.
__device__ __forceinline__ void trans64(
    const float* __restrict__ W, unsigned short* __restrict__ WT,
    int K, int N, int bk, int bn, int tid, float (*t)[65])
{
    const int tx = tid & 63, ty = tid >> 6;
    #pragma unroll
    for (int s = 0; s < 16; ++s)
        t[ty + 4 * s][tx] = W[(size_t)(bk + ty + 4 * s) * N + bn + tx];
    __syncthreads();
    const int c = tid & 31, rg = tid >> 5;
    #pragma unroll
    for (int s = 0; s < 8; ++s) {
        int r = rg + 8 * s;
        unsigned lo = f2bf(t[2 * c][r]);
        unsigned hi = f2bf(t[2 * c + 1][r]);
        *(unsigned*)(WT + (size_t)(bn + r) * K + bk + 2 * c) = lo | (hi << 16);
    }
}

// ---------------- GEMM1 (XCD-swizzled, dbuf) + weight transposes ------------
__global__ __launch_bounds__(256) void gemm1_fused(
    const unsigned short* __restrict__ xb,
    const unsigned short* __restrict__ W_inT,
    unsigned short* __restrict__ xrb,
    const float* __restrict__ W_out,
    const float* __restrict__ Wx,
    const float* __restrict__ Wdt,
    unsigned short* __restrict__ W_outT,
    unsigned short* __restrict__ W_xTp,
    unsigned short* __restrict__ W_dtTp)
{
    __shared__ char smem[32768];   // GEMM dbuf: As 16KB + Bs 16KB; transpose 16.6KB
    const int bid = blockIdx.x;
    const int tid = threadIdx.x;
    if (bid < 512) {
        unsigned short* As = (unsigned short*)smem;
        unsigned short* Bs = As + 8192;
        const int xcd = bid & 7, idx = bid >> 3;
        const int bx = (xcd & 3) * 8 + (idx & 7);     // 0..31
        const int by = (xcd >> 2) * 8 + (idx >> 3);   // 0..15
        gemm_core<4>(xb, W_inT, nullptr, xrb,
                     2048, 4096, 1024, 0, 1024, bx, by, As, Bs);
    } else if (bid < 1024) {
        int tt = bid - 512;
        trans64(W_out, W_outT, 2048, 1024, (tt >> 4) * 64, (tt & 15) * 64,
                tid, (float(*)[65])smem);
    } else if (bid < 1280) {
        int idx4 = (bid - 1024) * 256 + tid;
        int n = idx4 >> 9, k0 = (idx4 & 511) << 2;
        ushort4 o;
        o.x = f2bf((n < 96) ? Wx[(size_t)(k0 + 0) * 96 + n] : 0.f);
        o.y = f2bf((n < 96) ? Wx[(size_t)(k0 + 1) * 96 + n] : 0.f);
        o.z = f2bf((n < 96) ? Wx[(size_t)(k0 + 2) * 96 + n] : 0.f);
        o.w = f2bf((n < 96) ? Wx[(size_t)(k0 + 3) * 96 + n] : 0.f);
        *(ushort4*)(W_xTp + (size_t)idx4 * 4) = o;
    } else {
        int idx4 = (bid - 1280) * 256 + tid;
        int n = idx4 >> 5, k0 = (idx4 & 31) << 2;
        ushort4 o;
        o.x = f2bf((k0 + 0 < 64) ? Wdt[(size_t)(k0 + 0) * 2048 + n] : 0.f);
        o.y = f2bf((k0 + 1 < 64) ? Wdt[(size_t)(k0 + 1) * 2048 + n] : 0.f);
        o.z = f2bf((k0 + 2 < 64) ? Wdt[(size_t)(k0 + 2) * 2048 + n] : 0.f);
        o.w = f2bf((k0 + 3 < 64) ? Wdt[(size_t)(k0 + 3) * 2048 + n] : 0.f);
        *(ushort4*)(W_dtTp + (size_t)idx4 * 4) = o;
    }
}

// ---------------- prep: x -> bf16, W_in -> W_inT ----------------------------
__global__ __launch_bounds__(256) void prep(
    const float* __restrict__ x,
    const float* __restrict__ W_in,
    unsigned short* __restrict__ xb,
    unsigned short* __restrict__ W_inT)
{
    __shared__ float t[64][65];
    const int bid = blockIdx.x;
    const int tid = threadIdx.x;
    if (bid < 1024) {
        int i = bid * 256 + tid;
        float4 v0 = *(const float4*)(x + (size_t)i * 8);
        float4 v1 = *(const float4*)(x + (size_t)i * 8 + 4);
        ushort4 o0, o1;
        o0.x = f2bf(v0.x); o0.y = f2bf(v0.y); o0.z = f2bf(v0.z); o0.w = f2bf(v0.w);
        o1.x = f2bf(v1.x); o1.y = f2bf(v1.y); o1.z = f2bf(v1.z); o1.w = f2bf(v1.w);
        *(ushort4*)(xb + (size_t)i * 8) = o0;
        *(ushort4*)(xb + (size_t)i * 8 + 4) = o1;
    } else {
        int tt = bid - 1024;
        trans64(W_in, W_inT, 1024, 4096, (tt >> 6) * 64, (tt & 63) * 64, tid, t);
    }
}

// xdbl_b[2048][128] = bf16 sum of 16 bf16 split-K partials (fp32 accumulate).
__global__ __launch_bounds__(256) void reduce16(
    const unsigned short* __restrict__ P, unsigned short* __restrict__ dstb)
{
    int i = blockIdx.x * 256 + threadIdx.x;   // uint4 index, 32768 total
    float s[8] = {};
    #pragma unroll
    for (int k = 0; k < 16; ++k) {
        uint4 v = ((const uint4*)P)[i + (size_t)k * 32768];
        const unsigned short* pv = (const unsigned short*)&v;
        #pragma unroll
        for (int e = 0; e < 8; ++e) s[e] += bf2f(pv[e]);
    }
    unsigned short ob[8];
    #pragma unroll
    for (int e = 0; e < 8; ++e) ob[e] = f2bf(s[e]);
    ((uint4*)dstb)[i] = *(const uint4*)ob;
}

// out[2048][1024] = sum of 4 bf16 split-K partials (fp32 accumulate)
__global__ __launch_bounds__(256) void reduce4(
    const unsigned short* __restrict__ P, float* __restrict__ dst)
{
    int i = blockIdx.x * 256 + threadIdx.x;   // uint4 index, 262144 total
    float s[8] = {};
    #pragma unroll
    for (int k = 0; k < 4; ++k) {
        uint4 v = ((const uint4*)P)[i + (size_t)k * 262144];
        const unsigned short* pv = (const unsigned short*)&v;
        #pragma unroll
        for (int e = 0; e < 8; ++e) s[e] += bf2f(pv[e]);
    }
    ((float4*)dst)[i * 2]     = make_float4(s[0], s[1], s[2], s[3]);
    ((float4*)dst)[i * 2 + 1] = make_float4(s[4], s[5], s[6], s[7]);
}

// u(bf16) = silu(causal depthwise conv(xr_b[:, :2048]) + conv_b), 4 ch/thread
__global__ __launch_bounds__(256) void conv_silu(
    const unsigned short* __restrict__ xrb,
    const float* __restrict__ conv_w,
    const float* __restrict__ conv_b,
    unsigned short* __restrict__ ub)
{
    int t = blockIdx.x * 256 + threadIdx.x;
    int d4 = (t & 511) << 2;
    int r = t >> 9;
    int l = r & 1023, b = r >> 10;
    float4 cb4 = *(const float4*)(conv_b + d4);
    float acc[4] = {cb4.x, cb4.y, cb4.z, cb4.w};
    float4 cw0 = *(const float4*)(conv_w + (size_t)(d4 + 0) * 4);
    float4 cw1 = *(const float4*)(conv_w + (size_t)(d4 + 1) * 4);
    float4 cw2 = *(const float4*)(conv_w + (size_t)(d4 + 2) * 4);
    float4 cw3 = *(const float4*)(conv_w + (size_t)(d4 + 3) * 4);
    float w0a[4] = {cw0.x, cw0.y, cw0.z, cw0.w};
    float w1a[4] = {cw1.x, cw1.y, cw1.z, cw1.w};
    float w2a[4] = {cw2.x, cw2.y, cw2.z, cw2.w};
    float w3a[4] = {cw3.x, cw3.y, cw3.z, cw3.w};
    #pragma unroll
    for (int w = 0; w < 4; ++w) {
        int ls = l + w - 3;
        if (ls >= 0) {
            ushort4 xv = *(const ushort4*)(xrb + (((size_t)((b << 10) + ls)) << 12) + d4);
            acc[0] = fmaf(bf2f(xv.x), w0a[w], acc[0]);
            acc[1] = fmaf(bf2f(xv.y), w1a[w], acc[1]);
            acc[2] = fmaf(bf2f(xv.z), w2a[w], acc[2]);
            acc[3] = fmaf(bf2f(xv.w), w3a[w], acc[3]);
        }
    }
    ushort4 o;
    o.x = f2bf(silu_f(acc[0]));
    o.y = f2bf(silu_f(acc[1]));
    o.z = f2bf(silu_f(acc[2]));
    o.w = f2bf(silu_f(acc[3]));
    *(ushort4*)(ub + (size_t)t * 4) = o;
}

// ---------------- segmented selective scan (bf16 inputs) -------------------
#define SCAN_T 16
#define NSEG 8
#define SEGLEN 128

#define DPP_ADD(v, ctrl) ((v) + __int_as_float(__builtin_amdgcn_update_dpp( \
        0, __float_as_int(v), (ctrl), 0xF, 0xF, true)))

__global__ __launch_bounds__(256) void scan_pass1(
    const unsigned short* __restrict__ delta_b,
    const unsigned short* __restrict__ ub,
    const unsigned short* __restrict__ xdbl_b,  // [2048][128] bf16
    const float* __restrict__ A_log,
    float* __restrict__ stash)
{
    __shared__ float2 du[2][SCAN_T][17];
    __shared__ float  bs[2][SCAN_T][17];

    const int tid = threadIdx.x;
    const int dg = blockIdx.x, b = blockIdx.y, s = blockIdx.z;
    const int d0 = dg * 16;
    const int ch = tid >> 4, n = tid & 15;
    const float Aval = -__expf(A_log[(d0 + ch) * 16 + n]);
    const int sli = tid >> 4, sc = tid & 15;
    const int lbase = s * SEGLEN;

    float g_d, g_u, g_b;
    {
        size_t row = (size_t)(b << 10) + lbase + sli;
        g_d = bf2f(delta_b[(row << 11) + d0 + sc]);
        g_u = bf2f(ub[(row << 11) + d0 + sc]);
        g_b = bf2f(xdbl_b[(row << 7) + 64 + sc]);
    }
    du[0][sli][sc] = make_float2(g_d, g_u);
    bs[0][sli][sc] = g_b;
    __syncthreads();

    float h = 0.f, sd = 0.f;
    int cb = 0;
    for (int c = 0; c < SEGLEN / SCAN_T; ++c) {
        const bool more = (c + 1) < SEGLEN / SCAN_T;
        if (more) {
            size_t row = (size_t)(b << 10) + lbase + (c + 1) * SCAN_T + sli;
            g_d = bf2f(delta_b[(row << 11) + d0 + sc]);
            g_u = bf2f(ub[(row << 11) + d0 + sc]);
            g_b = bf2f(xdbl_b[(row << 7) + 64 + sc]);
        }
        float e_[SCAN_T], f_[SCAN_T];
        #pragma unroll
        for (int li = 0; li < SCAN_T; ++li) {
            float2 duv = du[cb][li][ch];
            float bv = bs[cb][li][n];
            e_[li] = __expf(duv.x * Aval);
            f_[li] = duv.x * bv * duv.y;
            sd += duv.x;
        }
        #pragma unroll
        for (int li = 0; li < SCAN_T; ++li)
            h = fmaf(e_[li], h, f_[li]);
        if (more) {
            du[cb ^ 1][sli][sc] = make_float2(g_d, g_u);
            bs[cb ^ 1][sli][sc] = g_b;
        }
        __syncthreads();
        cb ^= 1;
    }
    int j = (((b << 3) + s) * 128 + dg) * 256 + tid;
    stash[j] = __expf(Aval * sd);
    stash[j + 524288] = h;
}

__global__ __launch_bounds__(256) void scan_pass3(
    const unsigned short* __restrict__ delta_b,
    const unsigned short* __restrict__ ub,
    const unsigned short* __restrict__ xdbl_b,
    const float* __restrict__ A_log,
    const unsigned short* __restrict__ xrb,
    const float* __restrict__ stash,
    const float* __restrict__ Dv,
    unsigned short* __restrict__ ysb)
{
    __shared__ float2 du[2][SCAN_T][17];
    __shared__ float2 bc[2][SCAN_T][17];
    __shared__ float  rs[2][SCAN_T][17];

    const int tid = threadIdx.x;
    const int dg = blockIdx.x, b = blockIdx.y, s = blockIdx.z;
    const int d0 = dg * 16;
    const int ch = tid >> 4, n = tid & 15;
    const float Aval = -__expf(A_log[(d0 + ch) * 16 + n]);
    const float Dval = Dv[d0 + ch];
    const int sli = tid >> 4, sc = tid & 15;
    const int lbase = s * SEGLEN;

    float h = 0.f;
    for (int sp = 0; sp < s; ++sp) {
        int j = (((b << 3) + sp) * 128 + dg) * 256 + tid;
        h = fmaf(stash[j], h, stash[j + 524288]);
    }

    float g_d, g_u, g_b, g_c, g_r;
    {
        size_t row = (size_t)(b << 10) + lbase + sli;
        g_d = bf2f(delta_b[(row << 11) + d0 + sc]);
        g_u = bf2f(ub[(row << 11) + d0 + sc]);
        g_b = bf2f(xdbl_b[(row << 7) + 64 + sc]);
        g_c = bf2f(xdbl_b[(row << 7) + 80 + sc]);
        g_r = bf2f(xrb[(row << 12) + 2048 + d0 + sc]);
    }
    du[0][sli][sc] = make_float2(g_d, g_u);
    bc[0][sli][sc] = make_float2(g_b, g_c);
    rs[0][sli][sc] = g_r;
    __syncthreads();

    int cb = 0;
    for (int c = 0; c < SEGLEN / SCAN_T; ++c) {
        const int l0 = lbase + c * SCAN_T;
        const bool more = (c + 1) < SEGLEN / SCAN_T;
        if (more) {
            size_t row = (size_t)(b << 10) + l0 + SCAN_T + sli;
            g_d = bf2f(delta_b[(row << 11) + d0 + sc]);
            g_u = bf2f(ub[(row << 11) + d0 + sc]);
            g_b = bf2f(xdbl_b[(row << 7) + 64 + sc]);
            g_c = bf2f(xdbl_b[(row << 7) + 80 + sc]);
            g_r = bf2f(xrb[(row << 12) + 2048 + d0 + sc]);
        }
        float e_[SCAN_T], f_[SCAN_T], c_[SCAN_T];
        #pragma unroll
        for (int li = 0; li < SCAN_T; ++li) {
            float2 duv = du[cb][li][ch];
            float2 bcv = bc[cb][li][n];
            e_[li] = __expf(duv.x * Aval);
            f_[li] = duv.x * bcv.x * duv.y;
            c_[li] = bcv.y;
        }
        float mysum = 0.f;
        #pragma unroll
        for (int li = 0; li < SCAN_T; ++li) {
            h = fmaf(e_[li], h, f_[li]);
            float pv = h * c_[li];
            pv = DPP_ADD(pv, 0xB1);
            pv = DPP_ADD(pv, 0x4E);
            pv = DPP_ADD(pv, 0x141);
            pv = DPP_ADD(pv, 0x140);
            mysum = (n == li) ? pv : mysum;
        }
        {
            float2 duv = du[cb][n][ch];
            float resv = rs[cb][n][ch];
            float outv = (mysum + duv.y * Dval) * silu_f(resv);
            ysb[((size_t)((b << 10) + l0 + n) << 11) + d0 + ch] = f2bf(outv);
        }
        if (more) {
            du[cb ^ 1][sli][sc] = make_float2(g_d, g_u);
            bc[cb ^ 1][sli][sc] = make_float2(g_b, g_c);
            rs[cb ^ 1][sli][sc] = g_r;
        }
        __syncthreads();
        cb ^= 1;
    }
}

extern "C" void kernel_launch(void* const* d_in, const int* in_sizes, int n_in,
                              void* d_out, int out_size, void* d_ws, size_t ws_size,
                              hipStream_t stream)
{
    const float* x      = (const float*)d_in[0];
    const float* W_in   = (const float*)d_in[1];
    const float* conv_w = (const float*)d_in[2];
    const float* conv_b = (const float*)d_in[3];
    const float* W_x    = (const float*)d_in[4];
    const float* W_dt   = (const float*)d_in[5];
    const float* b_dt   = (const float*)d_in[6];
    const float* A_log  = (const float*)d_in[7];
    const float* Dv     = (const float*)d_in[8];
    const float* W_out  = (const float*)d_in[9];
    float* out = (float*)d_out;

    float* ws    = (float*)d_ws;
    unsigned short* P16b = (unsigned short*)(ws + (size_t)262144);   // 16 bf16 partials [2048][128]
    unsigned short* P4b  = (unsigned short*)(ws + (size_t)4456448);  // 4 bf16 partials [2048][1024]
    float* stash = ws + (size_t)12845056;            // 1,048,576 f (A_seg,B_seg)
    unsigned short* bfr = (unsigned short*)(ws + (size_t)13893632);
    unsigned short* xb      = bfr;                       // [2048][1024]
    unsigned short* W_inT   = bfr + (size_t)2097152;     // [4096][1024]
    unsigned short* W_xTp   = bfr + (size_t)6291456;     // [128][2048]
    unsigned short* W_dtTp  = bfr + (size_t)6553600;     // [2048][128]
    unsigned short* W_outT  = bfr + (size_t)6815744;     // [1024][2048]
    unsigned short* xrb     = bfr + (size_t)8912896;     // [2048][4096]
    unsigned short* ub      = bfr + (size_t)17301504;    // [2048][2048]
    unsigned short* delta_b = bfr + (size_t)21495808;    // [2048][2048]
    unsigned short* ysb     = bfr + (size_t)25690112;    // [2048][2048]
    unsigned short* xdbl_b  = bfr + (size_t)29884416;    // [2048][128]

    // 1. x -> bf16, W_in -> W_inT
    prep<<<2048, 256, 0, stream>>>(x, W_in, xb, W_inT);
    // 2. GEMM1 128² tiles, XCD-swizzled, dbuf K-loop (512 blocks) + transposes
    gemm1_fused<<<1536, 256, 0, stream>>>(xb, W_inT, xrb, W_out, W_x, W_dt,
                                          W_outT, W_xTp, W_dtTp);
    // 3. u(bf16) = silu(causal dwconv(xr[:, :2048]))
    conv_silu<<<4096, 256, 0, stream>>>(xrb, conv_w, conv_b, ub);
    // 4. xdbl_b = u @ W_x  64²-tile split-K=16 (1024 blocks), bf16 partials
    gemm64_bf16<5><<<dim3(2, 32, 16), 256, 0, stream>>>(ub, W_xTp, P16b, nullptr, 2048, 128, 2048, 128);
    reduce16<<<128, 256, 0, stream>>>(P16b, xdbl_b);
    // 5. delta(bf16) = softplus(xdbl @ W_dt + b_dt)  64²-tile (1024 blocks)
    gemm64_bf16<3><<<dim3(32, 32, 1), 256, 0, stream>>>(xdbl_b, W_dtTp, delta_b, b_dt, 2048, 2048, 128, 128);
    // 6. segmented scan: per-segment maps -> replay (h0 composed inline)
    scan_pass1<<<dim3(128, 2, 8), 256, 0, stream>>>(delta_b, ub, xdbl_b, A_log, stash);
    scan_pass3<<<dim3(128, 2, 8), 256, 0, stream>>>(delta_b, ub, xdbl_b, A_log, xrb, stash, Dv, ysb);
    // 7. out = ys @ W_out  128² tiles, split-K=4, XCD-swizzled, bf16 partials
    gemm7_swz<<<512, 256, 0, stream>>>(ysb, W_outT, P4b);
    reduce4<<<1024, 256, 0, stream>>>(P4b, out);
}